// Round 1
// baseline (560.407 us; speedup 1.0000x reference)
//
#include <hip/hip_runtime.h>
#include <hip/hip_fp16.h>

// Shapes (fixed by the reference setup_inputs)
#define NB 2
#define NH 16
#define NS 2048
#define ND 64

typedef __attribute__((ext_vector_type(8))) _Float16 half8;
typedef __attribute__((ext_vector_type(4))) float float4v;

static constexpr int NE = NB * NH * NS * ND;     // 4,194,304 elems per tensor
static constexpr int EPITCH = NS + 4;            // padded LDS row pitch (floats): 2052
static constexpr int TPB = 512;                  // 8 waves
static constexpr int LDS_BYTES = (16 * EPITCH + 16 + 16 * 64) * 4;  // e + invs + outb

// ---------------------------------------------------------------------------
// Kernel 1: RoPE(q), RoPE(k) -> fp16. One thread per (row, freq-pair) handles
// both q and k (shares sincos). Interleaved-pair rotation per lucidrains:
// out[2i] = x[2i]*cos - x[2i+1]*sin ; out[2i+1] = x[2i+1]*cos + x[2i]*sin
// freq_i = s * theta^(-i/32), i = 0..31
// ---------------------------------------------------------------------------
__global__ void rope_fp16_kernel(const float* __restrict__ q,
                                 const float* __restrict__ k,
                                 _Float16* __restrict__ qr,
                                 _Float16* __restrict__ kr) {
    int idx = blockIdx.x * blockDim.x + threadIdx.x;
    if (idx >= NE / 2) return;
    int i   = idx & 31;        // freq index
    int row = idx >> 5;        // (b*NH + h)*NS + s
    int s   = row & (NS - 1);

    // inv_freq = 10000^(-i/32) = exp(-i * ln(10000)/32)
    float inv_freq = expf((float)i * -0.2878231366242710f);
    float ang = (float)s * inv_freq;
    float sn, cs;
    sincosf(ang, &sn, &cs);    // precise version (args up to ~2048 rad)

    size_t base = (size_t)row * ND + 2 * i;
    float q0 = q[base], q1 = q[base + 1];
    float k0 = k[base], k1 = k[base + 1];
    qr[base]     = (_Float16)(q0 * cs - q1 * sn);
    qr[base + 1] = (_Float16)(q1 * cs + q0 * sn);
    kr[base]     = (_Float16)(k0 * cs - k1 * sn);
    kr[base + 1] = (_Float16)(k1 * cs + k0 * sn);
}

// ---------------------------------------------------------------------------
// Kernel 2: V [b,h,s,d] fp32 -> Vt [b,h,d,s] fp16 (so PV B-fragments are
// contiguous 16B loads). Writes coalesced; reads served by L2.
// ---------------------------------------------------------------------------
__global__ void vtrans_fp16_kernel(const float* __restrict__ v,
                                   _Float16* __restrict__ vt) {
    int idx = blockIdx.x * blockDim.x + threadIdx.x;
    if (idx >= NE) return;
    int s  = idx & (NS - 1);
    int d  = (idx >> 11) & (ND - 1);
    int bh = idx >> 17;
    vt[idx] = (_Float16)v[((size_t)bh * NS + s) * ND + d];
}

// ---------------------------------------------------------------------------
// Kernel 3: fused attention for one 16-row q-tile of one (b,h).
//   phase 1: e[r][c] = mask ? exp(qr.kr/8) : 0   (MFMA 16x16x32 f16)
//   phase 2: row sums -> invs[r]
//   phase 3a: score = e * invs (fp32, coalesced float4 writes)
//   phase 3b: PV MFMA on unnormalized e; cross-wave reduce via LDS atomics
//   phase 4: out = outb * invs
// MFMA fragment pattern (guide-verified, m89/m91): A lane holds row lane%16,
// k = (lane>>4)*8 + [0..7]; B identical on B^T rows; C/D: col=lane&15,
// row=(lane>>4)*4+reg. Any consistent A/B k-bijection is correct.
// ---------------------------------------------------------------------------
__global__ __launch_bounds__(TPB)
void attn_fused_kernel(const _Float16* __restrict__ qr,
                       const _Float16* __restrict__ kr,
                       const _Float16* __restrict__ vt,
                       const int* __restrict__ mask,
                       float* __restrict__ out,
                       float* __restrict__ score) {
    extern __shared__ float lds[];
    float* e    = lds;                    // [16][EPITCH]
    float* invs = lds + 16 * EPITCH;      // [16]
    float* outb = invs + 16;              // [16][64]

    int wg = blockIdx.x;
    int qt = wg & 127;                    // q-tile within (b,h)
    int bh = wg >> 7;
    int b  = bh >> 4;
    int q0 = qt * 16;

    int tid = threadIdx.x;
    int w   = tid >> 6;                   // wave 0..7
    int l   = tid & 63;
    int lm  = l & 15;
    int lp  = l >> 4;

    // zero the PV reduction buffer
    for (int i = tid; i < 16 * 64; i += TPB) outb[i] = 0.0f;

    // Preload Q A-fragments (invariant over all k-tiles)
    const _Float16* qrow = qr + ((size_t)bh * NS + q0 + lm) * ND;
    half8 a0 = *(const half8*)(qrow + lp * 8);
    half8 a1 = *(const half8*)(qrow + 32 + lp * 8);

    // ---- phase 1: QK^T -> masked exp -> e in LDS ----
    const int* mrow = mask + ((size_t)b * NS + q0) * NS;
    for (int kt = 0; kt < 16; ++kt) {
        int colbase = w * 256 + kt * 16;
        const _Float16* krow = kr + ((size_t)bh * NS + colbase + lm) * ND;
        half8 b0 = *(const half8*)(krow + lp * 8);
        half8 b1 = *(const half8*)(krow + 32 + lp * 8);
        float4v acc = {0.f, 0.f, 0.f, 0.f};
        acc = __builtin_amdgcn_mfma_f32_16x16x32_f16(a0, b0, acc, 0, 0, 0);
        acc = __builtin_amdgcn_mfma_f32_16x16x32_f16(a1, b1, acc, 0, 0, 0);
        int col = colbase + lm;
#pragma unroll
        for (int r = 0; r < 4; ++r) {
            int row = lp * 4 + r;
            int m = mrow[(size_t)row * NS + col];
            float ev = m ? __expf(acc[r] * 0.125f) : 0.0f;
            e[row * EPITCH + col] = ev;
        }
    }
    __syncthreads();

    // ---- phase 2: row sums ----
    {
        int r  = tid >> 5;                // 0..15
        int c0 = tid & 31;
        float ssum = 0.0f;
        for (int j = 0; j < 64; ++j) ssum += e[r * EPITCH + c0 + 32 * j];
#pragma unroll
        for (int off = 16; off; off >>= 1) ssum += __shfl_xor(ssum, off);
        if (c0 == 0) invs[r] = (ssum > 0.0f) ? (1.0f / ssum) : 0.0f;
    }
    __syncthreads();

    // ---- phase 3a: write normalized score ----
    {
        float* srow = score + ((size_t)bh * NS + q0) * NS;
        for (int i = tid; i < 16 * (NS / 4); i += TPB) {
            int r  = i >> 9;
            int c4 = (i & 511) * 4;
            float4v pe = *(float4v*)&e[r * EPITCH + c4];
            float iv = invs[r];
            pe *= iv;
            *(float4v*)&srow[(size_t)r * NS + c4] = pe;
        }
    }

    // ---- phase 3b: PV on unnormalized e ----
    {
        float4v acc4[4];
#pragma unroll
        for (int nt = 0; nt < 4; ++nt) acc4[nt] = (float4v){0.f, 0.f, 0.f, 0.f};
        for (int ks = 0; ks < 8; ++ks) {
            int kb = w * 256 + ks * 32;
            // A-fragment: p rows from LDS (fp32 -> fp16)
            float4v p0 = *(float4v*)&e[lm * EPITCH + kb + lp * 8];
            float4v p1 = *(float4v*)&e[lm * EPITCH + kb + lp * 8 + 4];
            half8 af;
#pragma unroll
            for (int i = 0; i < 4; ++i) af[i] = (_Float16)p0[i];
#pragma unroll
            for (int i = 0; i < 4; ++i) af[4 + i] = (_Float16)p1[i];
#pragma unroll
            for (int nt = 0; nt < 4; ++nt) {
                const _Float16* vrow = vt + ((size_t)bh * ND + nt * 16 + lm) * NS;
                half8 bf = *(const half8*)(vrow + kb + lp * 8);
                acc4[nt] = __builtin_amdgcn_mfma_f32_16x16x32_f16(af, bf, acc4[nt], 0, 0, 0);
            }
        }
#pragma unroll
        for (int nt = 0; nt < 4; ++nt)
#pragma unroll
            for (int r = 0; r < 4; ++r)
                atomicAdd(&outb[(lp * 4 + r) * 64 + nt * 16 + lm], acc4[nt][r]);
    }
    __syncthreads();

    // ---- phase 4: write out ----
    {
        float* orow = out + ((size_t)bh * NS + q0) * ND;
        for (int i = tid; i < 16 * 64; i += TPB) {
            int r = i >> 6;
            orow[i] = outb[i] * invs[r];
        }
    }
}

// ---------------------------------------------------------------------------
extern "C" void kernel_launch(void* const* d_in, const int* in_sizes, int n_in,
                              void* d_out, int out_size, void* d_ws, size_t ws_size,
                              hipStream_t stream) {
    const float* q    = (const float*)d_in[0];
    const float* k    = (const float*)d_in[1];
    const float* v    = (const float*)d_in[2];
    const int*   mask = (const int*)d_in[3];

    float* out   = (float*)d_out;            // [B,H,S,D]
    float* score = out + (size_t)NE;         // [B,H,S,S]

    _Float16* qr = (_Float16*)d_ws;
    _Float16* kr = qr + NE;
    _Float16* vt = kr + NE;

    // allow >64KB dynamic LDS (gfx950 supports 160KB/WG)
    static_assert(LDS_BYTES <= 160 * 1024, "LDS budget");
    (void)hipFuncSetAttribute(reinterpret_cast<const void*>(&attn_fused_kernel),
                              hipFuncAttributeMaxDynamicSharedMemorySize, LDS_BYTES);

    rope_fp16_kernel<<<dim3((NE / 2 + 255) / 256), dim3(256), 0, stream>>>(q, k, qr, kr);
    vtrans_fp16_kernel<<<dim3((NE + 255) / 256), dim3(256), 0, stream>>>(v, vt);
    attn_fused_kernel<<<dim3(NB * NH * (NS / 16)), dim3(TPB), LDS_BYTES, stream>>>(
        qr, kr, vt, mask, out, score);
}

// Round 2
// 366.118 us; speedup vs baseline: 1.5307x; 1.5307x over previous
//
#include <hip/hip_runtime.h>
#include <hip/hip_fp16.h>

// Shapes (fixed by the reference setup_inputs)
#define NB 2
#define NH 16
#define NS 2048
#define ND 64

typedef __attribute__((ext_vector_type(8))) _Float16 half8;
typedef __attribute__((ext_vector_type(4))) float float4v;

static constexpr int NE = NB * NH * NS * ND;     // 4,194,304 elems per tensor
static constexpr int EP = NS + 8;                // e pitch in halfs: 2056 (row base 16B-aligned)
static constexpr int TPB = 512;                  // 8 waves

// LDS layout (bytes): e[16][EP] fp16 | maskb[16][64] u32 | invs[16] f32 | outb[2][16*64] f32
static constexpr int LDS_E     = 16 * EP * 2;            // 65,792
static constexpr int LDS_MASK  = 16 * 64 * 4;            // 4,096
static constexpr int LDS_INVS  = 16 * 4;                 // 64
static constexpr int LDS_OUTB  = 2 * 16 * 64 * 4;        // 8,192
static constexpr int LDS_BYTES = LDS_E + LDS_MASK + LDS_INVS + LDS_OUTB;  // 78,144 -> 2 WG/CU

// ---------------------------------------------------------------------------
// Kernel 1: RoPE(q), RoPE(k) -> fp16.
// ---------------------------------------------------------------------------
__global__ void rope_fp16_kernel(const float* __restrict__ q,
                                 const float* __restrict__ k,
                                 _Float16* __restrict__ qr,
                                 _Float16* __restrict__ kr) {
    int idx = blockIdx.x * blockDim.x + threadIdx.x;
    if (idx >= NE / 2) return;
    int i   = idx & 31;        // freq index
    int row = idx >> 5;        // (b*NH + h)*NS + s
    int s   = row & (NS - 1);

    float inv_freq = expf((float)i * -0.2878231366242710f);  // 10000^(-i/32)
    float ang = (float)s * inv_freq;
    float sn, cs;
    sincosf(ang, &sn, &cs);

    size_t base = (size_t)row * ND + 2 * i;
    float q0 = q[base], q1 = q[base + 1];
    float k0 = k[base], k1 = k[base + 1];
    qr[base]     = (_Float16)(q0 * cs - q1 * sn);
    qr[base + 1] = (_Float16)(q1 * cs + q0 * sn);
    kr[base]     = (_Float16)(k0 * cs - k1 * sn);
    kr[base + 1] = (_Float16)(k1 * cs + k0 * sn);
}

// ---------------------------------------------------------------------------
// Kernel 2: V [b,h,s,d] fp32 -> Vt [b,h,d,s] fp16.
// ---------------------------------------------------------------------------
__global__ void vtrans_fp16_kernel(const float* __restrict__ v,
                                   _Float16* __restrict__ vt) {
    int idx = blockIdx.x * blockDim.x + threadIdx.x;
    if (idx >= NE) return;
    int s  = idx & (NS - 1);
    int d  = (idx >> 11) & (ND - 1);
    int bh = idx >> 17;
    vt[idx] = (_Float16)v[((size_t)bh * NS + s) * ND + d];
}

// ---------------------------------------------------------------------------
// Kernel 3: bit-pack mask int32 [B,1,S,S] -> uint32 [B][S][S/32] via ballot.
// ---------------------------------------------------------------------------
__global__ void maskpack_kernel(const int* __restrict__ mask,
                                unsigned int* __restrict__ mp) {
    size_t idx = (size_t)blockIdx.x * 256 + threadIdx.x;   // over NB*NS*NS
    unsigned long long bal = __ballot(mask[idx] != 0);
    int l = threadIdx.x & 63;
    if (l == 0)       mp[idx >> 5] = (unsigned int)bal;
    else if (l == 32) mp[idx >> 5] = (unsigned int)(bal >> 32);
}

// ---------------------------------------------------------------------------
// Kernel 4: fused attention, one 16-row q-tile per WG, 8 waves.
//   phase 1: e[r][c] = maskbit ? exp(qr.kr/8) : 0  (fp16 in LDS, MFMA 16x16x32)
//   phase 2: row sums -> invs
//   phase 3a: score = e * invs (float4 coalesced)
//   phase 3b: PV MFMA; wave w owns (d-block w&3, K-half w>>2) -> plain stores
//   phase 4: out = (outb0+outb1) * invs
// ---------------------------------------------------------------------------
__global__ __launch_bounds__(TPB)
void attn_fused_kernel(const _Float16* __restrict__ qr,
                       const _Float16* __restrict__ kr,
                       const _Float16* __restrict__ vt,
                       const unsigned int* __restrict__ mp,
                       float* __restrict__ out,
                       float* __restrict__ score) {
    extern __shared__ char lds_raw[];
    _Float16*     e     = (_Float16*)lds_raw;                       // [16][EP]
    unsigned int* maskb = (unsigned int*)(lds_raw + LDS_E);         // [16][64]
    float*        invs  = (float*)(lds_raw + LDS_E + LDS_MASK);     // [16]
    float*        outb  = invs + 16;                                // [2][16*64]

    // XCD-aware bijective swizzle: 4096 WGs, 8 XCDs -> contiguous 512 per XCD
    int wgid = (blockIdx.x & 7) * 512 + (blockIdx.x >> 3);
    int qt = wgid & 127;
    int bh = wgid >> 7;
    int b  = bh >> 4;
    int q0 = qt * 16;

    int tid = threadIdx.x;
    int w   = tid >> 6;                   // wave 0..7
    int l   = tid & 63;
    int lm  = l & 15;
    int lp  = l >> 4;

    // stage packed mask rows q0..q0+15 (4KB, coalesced)
    {
        const unsigned int* mrow = mp + ((size_t)b * NS + q0) * 64;
        for (int i = tid; i < 16 * 64; i += TPB) maskb[i] = mrow[i];
    }

    // Preload Q A-fragments (row = q0+lm, k = lp*8 + [0..7] (+32))
    const _Float16* qrow = qr + ((size_t)bh * NS + q0 + lm) * ND;
    half8 a0 = *(const half8*)(qrow + lp * 8);
    half8 a1 = *(const half8*)(qrow + 32 + lp * 8);
    __syncthreads();

    // ---- phase 1: QK^T -> masked exp -> e (fp16) ----
#pragma unroll 2
    for (int kt = 0; kt < 16; ++kt) {
        int colbase = w * 256 + kt * 16;
        const _Float16* krow = kr + ((size_t)bh * NS + colbase + lm) * ND;
        half8 b0 = *(const half8*)(krow + lp * 8);
        half8 b1 = *(const half8*)(krow + 32 + lp * 8);
        float4v acc = {0.f, 0.f, 0.f, 0.f};
        acc = __builtin_amdgcn_mfma_f32_16x16x32_f16(a0, b0, acc, 0, 0, 0);
        acc = __builtin_amdgcn_mfma_f32_16x16x32_f16(a1, b1, acc, 0, 0, 0);
        int col  = colbase + lm;
        int word = col >> 5;                       // same word for all 16 cols of tile
        unsigned int bitm = 1u << (col & 31);
#pragma unroll
        for (int r = 0; r < 4; ++r) {
            int row = lp * 4 + r;
            unsigned int mw = maskb[row * 64 + word];   // broadcast read
            float ev = (mw & bitm) ? __expf(acc[r] * 0.125f) : 0.0f;
            e[row * EP + col] = (_Float16)ev;
        }
    }
    __syncthreads();

    // ---- phase 2: row sums ----
    {
        int r = tid >> 5, c = tid & 31;
        const _Float16* er = e + r * EP;
        float s = 0.0f;
#pragma unroll
        for (int j = 0; j < 8; ++j) {
            half8 hv = *(const half8*)(er + c * 8 + j * 256);
#pragma unroll
            for (int t = 0; t < 8; ++t) s += (float)hv[t];
        }
#pragma unroll
        for (int off = 16; off; off >>= 1) s += __shfl_xor(s, off);
        if (c == 0) invs[r] = (s > 0.0f) ? (1.0f / s) : 0.0f;
    }
    __syncthreads();

    // ---- phase 3a: write normalized score ----
    {
        float* srow = score + ((size_t)bh * NS + q0) * NS;
        for (int i = tid; i < 16 * 256; i += TPB) {      // half8 chunks
            int r  = i >> 8;
            int ch = i & 255;
            half8 hv = *(const half8*)(e + r * EP + ch * 8);
            float iv = invs[r];
            float4v f0, f1;
#pragma unroll
            for (int t = 0; t < 4; ++t) { f0[t] = (float)hv[t] * iv; f1[t] = (float)hv[4 + t] * iv; }
            float4v* dst = (float4v*)(srow + (size_t)r * NS + ch * 8);
            dst[0] = f0;
            dst[1] = f1;
        }
    }

    // ---- phase 3b: PV; wave w owns d-block (w&3), K-half (w>>2) ----
    {
        int nt = w & 3, kh = w >> 2;
        const _Float16* vrow = vt + ((size_t)bh * ND + nt * 16 + lm) * NS + kh * 1024 + lp * 8;
        const _Float16* ep   = e + lm * EP + kh * 1024 + lp * 8;
        float4v acc = {0.f, 0.f, 0.f, 0.f};
#pragma unroll 4
        for (int ks = 0; ks < 32; ++ks) {
            half8 af = *(const half8*)(ep + ks * 32);
            half8 bf = *(const half8*)(vrow + ks * 32);
            acc = __builtin_amdgcn_mfma_f32_16x16x32_f16(af, bf, acc, 0, 0, 0);
        }
#pragma unroll
        for (int r = 0; r < 4; ++r)
            outb[kh * 1024 + (lp * 4 + r) * 64 + nt * 16 + lm] = acc[r];
    }
    __syncthreads();

    // ---- phase 4: out = (outb0 + outb1) * invs ----
    {
        float* orow = out + ((size_t)bh * NS + q0) * ND;
        for (int i = tid; i < 16 * 64; i += TPB) {
            int r = i >> 6;
            orow[i] = (outb[i] + outb[1024 + i]) * invs[r];
        }
    }
}

// ---------------------------------------------------------------------------
extern "C" void kernel_launch(void* const* d_in, const int* in_sizes, int n_in,
                              void* d_out, int out_size, void* d_ws, size_t ws_size,
                              hipStream_t stream) {
    const float* q    = (const float*)d_in[0];
    const float* k    = (const float*)d_in[1];
    const float* v    = (const float*)d_in[2];
    const int*   mask = (const int*)d_in[3];

    float* out   = (float*)d_out;            // [B,H,S,D]
    float* score = out + (size_t)NE;         // [B,H,S,S]

    _Float16* qrw = (_Float16*)d_ws;
    _Float16* krw = qrw + NE;
    _Float16* vtw = krw + NE;
    unsigned int* mp = (unsigned int*)(vtw + NE);   // NB*NS*NS/32 = 262,144 words

    static_assert(LDS_BYTES <= 160 * 1024, "LDS budget");
    (void)hipFuncSetAttribute(reinterpret_cast<const void*>(&attn_fused_kernel),
                              hipFuncAttributeMaxDynamicSharedMemorySize, LDS_BYTES);

    rope_fp16_kernel<<<dim3((NE / 2 + 255) / 256), dim3(256), 0, stream>>>(q, k, qrw, krw);
    vtrans_fp16_kernel<<<dim3((NE + 255) / 256), dim3(256), 0, stream>>>(v, vtw);
    maskpack_kernel<<<dim3(NB * NS * NS / 256), dim3(256), 0, stream>>>(mask, mp);
    attn_fused_kernel<<<dim3(NB * NH * (NS / 16)), dim3(TPB), LDS_BYTES, stream>>>(
        qrw, krw, vtw, mp, out, score);
}